// Round 9
// baseline (1543.829 us; speedup 1.0000x reference)
//
#include <hip/hip_runtime.h>
#include <math.h>

#define EMB   1024
#define HEADS 16
#define ATTND 64
#define BB    2
#define SS    2048
#define HD    (HEADS * ATTND)   // 1024
#define MTOT  (BB * SS)         // 4096

typedef unsigned short u16;
using u16x4  = __attribute__((ext_vector_type(4))) unsigned short;
using short8 = __attribute__((ext_vector_type(8))) short;

__device__ __forceinline__ u16 f2bf(float f) {
    union { float f; unsigned u; } x; x.f = f;
    unsigned r = x.u + 0x7fffu + ((x.u >> 16) & 1u);   // round-nearest-even
    return (u16)(r >> 16);
}
__device__ __forceinline__ float bf2f(u16 h) {
    union { unsigned u; float f; } x; x.u = ((unsigned)h) << 16;
    return x.f;
}

// ---------------------------------------------------------------------------
// Fused projection GEMMs (plain fp32 VALU — diagnostic anchor, no MFMA).
// out[b,h,s,d] = sum_e X[b,s,e] * W[e, h*64+d];  bf16 out in (B,H,S,D).
// blockIdx.z selects {q,k,v}. 64x64 tile, 256 threads, 4x4 per thread.
// ---------------------------------------------------------------------------
__global__ __launch_bounds__(256) void proj_kernel(const float* __restrict__ Xq,
                                                   const float* __restrict__ Xk,
                                                   const float* __restrict__ Xv,
                                                   const float* __restrict__ Wq,
                                                   const float* __restrict__ Wk,
                                                   const float* __restrict__ Wv,
                                                   u16* __restrict__ oq,
                                                   u16* __restrict__ ok,
                                                   u16* __restrict__ ov) {
    __shared__ float As[64][17];   // padded
    __shared__ float Ws[16][64];
    const float* X; const float* W; u16* out;
    if (blockIdx.z == 0)      { X = Xq; W = Wq; out = oq; }
    else if (blockIdx.z == 1) { X = Xk; W = Wk; out = ok; }
    else                      { X = Xv; W = Wv; out = ov; }

    const int row0 = blockIdx.x * 64;
    const int col0 = blockIdx.y * 64;
    const int tid  = threadIdx.x;
    const int tx   = tid & 15;
    const int ty   = tid >> 4;
    float acc[4][4] = {};

    for (int k0 = 0; k0 < EMB; k0 += 16) {
#pragma unroll
        for (int i = 0; i < 4; ++i) {
            int idx = tid + i * 256;
            int r = idx >> 4, c = idx & 15;
            As[r][c] = X[(size_t)(row0 + r) * EMB + k0 + c];
        }
#pragma unroll
        for (int i = 0; i < 4; ++i) {
            int idx = tid + i * 256;
            int r = idx >> 6, c = idx & 63;
            Ws[r][c] = W[(size_t)(k0 + r) * HD + col0 + c];
        }
        __syncthreads();
#pragma unroll
        for (int kk = 0; kk < 16; ++kk) {
            float a[4], b[4];
#pragma unroll
            for (int i = 0; i < 4; ++i) a[i] = As[ty * 4 + i][kk];
#pragma unroll
            for (int j = 0; j < 4; ++j) b[j] = Ws[kk][tx * 4 + j];
#pragma unroll
            for (int i = 0; i < 4; ++i)
#pragma unroll
                for (int j = 0; j < 4; ++j) acc[i][j] += a[i] * b[j];
        }
        __syncthreads();
    }
    // 64-wide col tile == one head: h = blockIdx.y
    const int h = col0 >> 6;
    const int dbase = tx * 4;
#pragma unroll
    for (int i = 0; i < 4; ++i) {
        int m = row0 + ty * 4 + i;
        int b = m >> 11;           // m / SS
        int s = m & (SS - 1);
        u16x4 o;
#pragma unroll
        for (int j = 0; j < 4; ++j) o[j] = f2bf(acc[i][j]);
        *(u16x4*)&out[(((size_t)(b * HEADS + h)) * SS + s) * ATTND + dbase] = o;
    }
}

// ---------------------------------------------------------------------------
// Flash attention (fp32 math, bf16 in/out, causal). 1 block = (b*h, 64 q-rows).
// 256 threads: row = tid>>2, g = tid&3 (16-wide d/key slices). UNCHANGED (R4).
// ---------------------------------------------------------------------------
__global__ __launch_bounds__(256) void flash_kernel(const u16* __restrict__ fq,
                                                    const u16* __restrict__ fk,
                                                    const u16* __restrict__ fv,
                                                    u16* __restrict__ attn) {
    __shared__ float Ks[64][65];
    __shared__ float Vs[64][64];
    __shared__ float Ps[64][65];
    const int bh  = blockIdx.x;            // b*HEADS + h
    const int qb  = blockIdx.y;
    const int b   = bh / HEADS;
    const int h   = bh % HEADS;
    const int tid = threadIdx.x;
    const int row = tid >> 2;
    const int g   = tid & 3;
    const float scale = 0.125f;            // 1/sqrt(64)
    const size_t base = (size_t)bh * SS * ATTND;
    const int qr0 = qb * 64;

    float qreg[64];
#pragma unroll
    for (int i = 0; i < 8; ++i) {
        short8 v = *(const short8*)&fq[base + (size_t)(qr0 + row) * ATTND + i * 8];
#pragma unroll
        for (int j = 0; j < 8; ++j) qreg[i * 8 + j] = bf2f((u16)v[j]);
    }

    float m = -1e30f, l = 0.f;
    float o[16];
#pragma unroll
    for (int i = 0; i < 16; ++i) o[i] = 0.f;

    for (int kb = 0; kb <= qb; ++kb) {
        __syncthreads();
        const int kr0 = kb * 64;
#pragma unroll
        for (int it = 0; it < 4; ++it) {
            int idx4 = tid + it * 256;          // 1024 quads = 4096 elems
            int r = idx4 >> 4, d = (idx4 & 15) * 4;
            u16x4 kv = *(const u16x4*)&fk[base + (size_t)(kr0 + r) * ATTND + d];
            u16x4 vv = *(const u16x4*)&fv[base + (size_t)(kr0 + r) * ATTND + d];
#pragma unroll
            for (int j = 0; j < 4; ++j) {
                Ks[r][d + j] = bf2f(kv[j]);
                Vs[r][d + j] = bf2f(vv[j]);
            }
        }
        __syncthreads();

#pragma unroll 1
        for (int jj = 0; jj < 16; ++jj) {
            int j = g * 16 + jj;
            float s = 0.f;
#pragma unroll
            for (int dd = 0; dd < 64; ++dd) s += qreg[dd] * Ks[j][dd];
            Ps[row][j] = s * scale;
        }
        __syncthreads();

        const bool diag = (kb == qb);
        float bmax = -1e30f;
        for (int j = 0; j < 64; ++j) {
            float s = Ps[row][j];
            if (diag && j > row) s = -1e30f;
            bmax = fmaxf(bmax, s);
        }
        float newm = fmaxf(m, bmax);
        float corr = __expf(m - newm);
#pragma unroll
        for (int i = 0; i < 16; ++i) o[i] *= corr;
        float bsum = 0.f;
#pragma unroll 1
        for (int j = 0; j < 64; ++j) {
            float s = Ps[row][j];
            float p = (diag && j > row) ? 0.f : __expf(s - newm);
            bsum += p;
#pragma unroll
            for (int dd = 0; dd < 16; ++dd) o[dd] += p * Vs[j][g * 16 + dd];
        }
        l = l * corr + bsum;
        m = newm;
    }

    const float inv = 1.f / l;
    size_t oaddr = ((size_t)(b * SS + qr0 + row)) * HD + h * ATTND + g * 16;
#pragma unroll
    for (int i = 0; i < 4; ++i) {
        u16x4 ov;
#pragma unroll
        for (int j = 0; j < 4; ++j) ov[j] = f2bf(o[i * 4 + j] * inv);
        *(u16x4*)&attn[oaddr + i * 4] = ov;
    }
}

// ---------------------------------------------------------------------------
// Output projection (plain fp32 VALU): out[m,e] = sum_f A[m,f]*Wo[e,f] + b[e].
// A: attn bf16 (M x HD, k-contig, converted on LDS stage). Wo: fp32 (EMB x HD).
// fp32 output (d_out is float* — PROVEN by out_npz_mb=15.5 > 8.4 MB bf16 raw).
// ---------------------------------------------------------------------------
__global__ __launch_bounds__(256) void outproj_kernel(const u16* __restrict__ A,
                                                      const float* __restrict__ W,
                                                      const float* __restrict__ bias,
                                                      float* __restrict__ out) {
    __shared__ float As[64][17];
    __shared__ float Ws2[64][17];
    const int row0 = blockIdx.x * 64;
    const int col0 = blockIdx.y * 64;
    const int tid  = threadIdx.x;
    const int tx   = tid & 15;
    const int ty   = tid >> 4;
    float acc[4][4] = {};

    for (int k0 = 0; k0 < HD; k0 += 16) {
#pragma unroll
        for (int i = 0; i < 4; ++i) {
            int idx = tid + i * 256;
            int r = idx >> 4, c = idx & 15;
            As[r][c]  = bf2f(A[(size_t)(row0 + r) * HD + k0 + c]);
            Ws2[r][c] = W[(size_t)(col0 + r) * HD + k0 + c];
        }
        __syncthreads();
#pragma unroll
        for (int kk = 0; kk < 16; ++kk) {
            float a[4], b[4];
#pragma unroll
            for (int i = 0; i < 4; ++i) a[i] = As[ty * 4 + i][kk];
#pragma unroll
            for (int j = 0; j < 4; ++j) b[j] = Ws2[tx * 4 + j][kk];
#pragma unroll
            for (int i = 0; i < 4; ++i)
#pragma unroll
                for (int j = 0; j < 4; ++j) acc[i][j] += a[i] * b[j];
        }
        __syncthreads();
    }
#pragma unroll
    for (int i = 0; i < 4; ++i) {
        int mrow = row0 + ty * 4 + i;
        int cb = col0 + tx * 4;
        float4 v;
        v.x = acc[i][0] + bias[cb + 0];
        v.y = acc[i][1] + bias[cb + 1];
        v.z = acc[i][2] + bias[cb + 2];
        v.w = acc[i][3] + bias[cb + 3];
        *(float4*)&out[(size_t)mrow * EMB + cb] = v;
    }
}

// ---------------------------------------------------------------------------
extern "C" void kernel_launch(void* const* d_in, const int* in_sizes, int n_in,
                              void* d_out, int out_size, void* d_ws, size_t ws_size,
                              hipStream_t stream) {
    const float* q     = (const float*)d_in[0];
    const float* k     = (const float*)d_in[1];
    const float* v     = (const float*)d_in[2];
    // d_in[3] = mask (tril by construction; causal handled analytically)
    const float* w_q   = (const float*)d_in[4];
    const float* w_k   = (const float*)d_in[5];
    const float* w_v   = (const float*)d_in[6];
    const float* out_w = (const float*)d_in[7];
    const float* out_b = (const float*)d_in[8];

    u16* ws = (u16*)d_ws;
    const size_t MK = (size_t)MTOT * EMB;        // 4,194,304 elems
    u16* fq   = ws;                               // (B,H,S,D) bf16, 8 MiB
    u16* fk   = ws + MK;
    u16* fv   = ws + 2 * MK;
    u16* attn = ws + 3 * MK;                      // (B,S,HD) bf16, 8 MiB
    // total ws use: 32 MiB (same layout as R4, which ran without NaN)

    dim3 gproj(MTOT / 64, HD / 64, 3);            // (64,16,3)
    proj_kernel<<<gproj, 256, 0, stream>>>(q, k, v, w_q, w_k, w_v, fq, fk, fv);

    dim3 gattn(BB * HEADS, SS / 64);              // (32,32)
    flash_kernel<<<gattn, 256, 0, stream>>>(fq, fk, fv, attn);

    dim3 gout(MTOT / 64, EMB / 64);               // (64,16)
    outproj_kernel<<<gout, 256, 0, stream>>>(attn, out_w, out_b, (float*)d_out);
}

// Round 10
// 376.971 us; speedup vs baseline: 4.0954x; 4.0954x over previous
//
#include <hip/hip_runtime.h>
#include <math.h>

#define EMB   1024
#define HEADS 16
#define ATTND 64
#define BB    2
#define SS    2048
#define HD    (HEADS * ATTND)   // 1024
#define MTOT  (BB * SS)         // 4096

typedef unsigned short u16;
using u16x4  = __attribute__((ext_vector_type(4))) unsigned short;
using short8 = __attribute__((ext_vector_type(8))) short;
using f32x4  = __attribute__((ext_vector_type(4))) float;

__device__ __forceinline__ u16 f2bf(float f) {
    union { float f; unsigned u; } x; x.f = f;
    unsigned r = x.u + 0x7fffu + ((x.u >> 16) & 1u);   // round-nearest-even
    return (u16)(r >> 16);
}
__device__ __forceinline__ float bf2f(u16 h) {
    union { unsigned u; float f; } x; x.u = ((unsigned)h) << 16;
    return x.f;
}

// ---------------------------------------------------------------------------
// Fused projection GEMMs, fp32 inputs -> bf16 LDS -> MFMA -> bf16 (B,H,S,D).
// UNCHANGED from R4 (staging audited correct: 16 elems/thread both operands).
// ---------------------------------------------------------------------------
__global__ __launch_bounds__(256) void proj_mfma_kernel(const float* __restrict__ Xq,
                                                        const float* __restrict__ Xk,
                                                        const float* __restrict__ Xv,
                                                        const float* __restrict__ Wq,
                                                        const float* __restrict__ Wk,
                                                        const float* __restrict__ Wv,
                                                        u16* __restrict__ oq,
                                                        u16* __restrict__ ok,
                                                        u16* __restrict__ ov) {
    __shared__ u16 As[128][40];
    __shared__ u16 Bs[128][40];
    const float* X; const float* W; u16* out;
    if (blockIdx.z == 0)      { X = Xq; W = Wq; out = oq; }
    else if (blockIdx.z == 1) { X = Xk; W = Wk; out = ok; }
    else                      { X = Xv; W = Wv; out = ov; }

    const int row0 = blockIdx.x * 128;
    const int col0 = blockIdx.y * 128;
    const int tid  = threadIdx.x;
    const int lane = tid & 63;
    const int wid  = tid >> 6;
    const int wm   = wid >> 1, wn = wid & 1;
    const int l15  = lane & 15, kh = lane >> 4;
    const int srow = tid >> 1, sh = tid & 1;
    const int bn4  = (tid & 31) * 4;
    const int bk   = tid >> 5;

    f32x4 acc[4][4];
#pragma unroll
    for (int i = 0; i < 4; ++i)
#pragma unroll
        for (int j = 0; j < 4; ++j) acc[i][j] = (f32x4){0.f, 0.f, 0.f, 0.f};

    for (int k0 = 0; k0 < EMB; k0 += 32) {
        float4 a4[4], w4[4];
#pragma unroll
        for (int j = 0; j < 4; ++j)
            a4[j] = *(const float4*)&X[(size_t)(row0 + srow) * EMB + k0 + sh * 16 + j * 4];
#pragma unroll
        for (int i = 0; i < 4; ++i)
            w4[i] = *(const float4*)&W[(size_t)(k0 + bk + i * 8) * HD + col0 + bn4];

        __syncthreads();
        short8 p0, p1;
        p0[0] = (short)f2bf(a4[0].x); p0[1] = (short)f2bf(a4[0].y);
        p0[2] = (short)f2bf(a4[0].z); p0[3] = (short)f2bf(a4[0].w);
        p0[4] = (short)f2bf(a4[1].x); p0[5] = (short)f2bf(a4[1].y);
        p0[6] = (short)f2bf(a4[1].z); p0[7] = (short)f2bf(a4[1].w);
        p1[0] = (short)f2bf(a4[2].x); p1[1] = (short)f2bf(a4[2].y);
        p1[2] = (short)f2bf(a4[2].z); p1[3] = (short)f2bf(a4[2].w);
        p1[4] = (short)f2bf(a4[3].x); p1[5] = (short)f2bf(a4[3].y);
        p1[6] = (short)f2bf(a4[3].z); p1[7] = (short)f2bf(a4[3].w);
        *(short8*)&As[srow][sh * 16]     = p0;
        *(short8*)&As[srow][sh * 16 + 8] = p1;
#pragma unroll
        for (int i = 0; i < 4; ++i) {
            int kk = bk + i * 8;
            Bs[bn4 + 0][kk] = f2bf(w4[i].x);
            Bs[bn4 + 1][kk] = f2bf(w4[i].y);
            Bs[bn4 + 2][kk] = f2bf(w4[i].z);
            Bs[bn4 + 3][kk] = f2bf(w4[i].w);
        }
        __syncthreads();

        short8 af[4], bfr[4];
#pragma unroll
        for (int mi = 0; mi < 4; ++mi)
            af[mi] = *(const short8*)&As[wm * 64 + mi * 16 + l15][kh * 8];
#pragma unroll
        for (int ni = 0; ni < 4; ++ni)
            bfr[ni] = *(const short8*)&Bs[wn * 64 + ni * 16 + l15][kh * 8];
#pragma unroll
        for (int mi = 0; mi < 4; ++mi)
#pragma unroll
            for (int ni = 0; ni < 4; ++ni)
                acc[mi][ni] = __builtin_amdgcn_mfma_f32_16x16x32_bf16(
                    af[mi], bfr[ni], acc[mi][ni], 0, 0, 0);
    }

#pragma unroll
    for (int mi = 0; mi < 4; ++mi)
#pragma unroll
        for (int ni = 0; ni < 4; ++ni)
#pragma unroll
            for (int r = 0; r < 4; ++r) {
                int m   = row0 + wm * 64 + mi * 16 + kh * 4 + r;
                int col = col0 + wn * 64 + ni * 16 + l15;
                int b = m >> 11, s = m & (SS - 1);
                int h = col >> 6, d = col & 63;
                out[(((size_t)(b * HEADS + h)) * SS + s) * ATTND + d] =
                    f2bf(acc[mi][ni][r]);
            }
}

// ---------------------------------------------------------------------------
// MFMA flash attention, causal. Block = (b*h, 64 q-rows), 4 waves.
// Wave w owns q-rows [w*16, w*16+16). K lds [key][d] bf16, V lds transposed
// [d][key] bf16, both XOR-swizzled (byte ^= (row&7)<<4). P relayout D->A via
// per-wave LDS (same-wave DS ordering, no barrier). Online softmax per lane
// over 4 rows; 16-lane shfl_xor reductions (l15 bits only).
// ---------------------------------------------------------------------------
__global__ __launch_bounds__(256) void flash_mfma_kernel(const u16* __restrict__ fq,
                                                         const u16* __restrict__ fk,
                                                         const u16* __restrict__ fv,
                                                         u16* __restrict__ attn) {
    __shared__ u16 Klds[64 * 64];        // 8 KB
    __shared__ u16 Vtlds[64 * 64];       // 8 KB
    __shared__ u16 Plds[4][16 * 64];     // 8 KB (per-wave 2 KB)
    const int bh  = blockIdx.x;                     // b*HEADS + h
    const int qb  = (int)gridDim.y - 1 - (int)blockIdx.y;  // long blocks first
    const int b   = bh / HEADS;
    const int h   = bh % HEADS;
    const int tid = threadIdx.x;
    const int w   = tid >> 6;
    const int lane = tid & 63;
    const int l15 = lane & 15, kh = lane >> 4;
    const size_t base = (size_t)bh * SS * ATTND;
    const int qr0 = qb * 64;

    // Q A-frags (row=l15, k=kk*32+kh*8+j) straight from global bf16
    const int qrow = qr0 + w * 16 + l15;
    short8 qf[2];
    qf[0] = *(const short8*)&fq[base + (size_t)qrow * ATTND + kh * 8];
    qf[1] = *(const short8*)&fq[base + (size_t)qrow * ATTND + 32 + kh * 8];

    f32x4 accO[4];
#pragma unroll
    for (int ni = 0; ni < 4; ++ni) accO[ni] = (f32x4){0.f, 0.f, 0.f, 0.f};
    float mrow[4] = {-1e30f, -1e30f, -1e30f, -1e30f};
    float lrow[4] = {0.f, 0.f, 0.f, 0.f};

    const int skey = tid & 63;
    const int sd0  = (tid >> 6) * 16;
    const int grow_base = qr0 + w * 16 + kh * 4;   // D-frag row base

    for (int kb = 0; kb <= qb; ++kb) {
        const int kr0 = kb * 64;
        // global loads (before barrier; no LDS touch yet)
        short8 k0v = *(const short8*)&fk[base + (size_t)(kr0 + skey) * ATTND + sd0];
        short8 k1v = *(const short8*)&fk[base + (size_t)(kr0 + skey) * ATTND + sd0 + 8];
        short8 v0v = *(const short8*)&fv[base + (size_t)(kr0 + skey) * ATTND + sd0];
        short8 v1v = *(const short8*)&fv[base + (size_t)(kr0 + skey) * ATTND + sd0 + 8];
        __syncthreads();                 // all waves done with previous K/V
        {
            int kbyte0 = skey * 128 + sd0 * 2;
            int kswz   = (skey & 7) << 4;
            *(short8*)((char*)Klds + ((kbyte0) ^ kswz))      = k0v;
            *(short8*)((char*)Klds + ((kbyte0 + 16) ^ kswz)) = k1v;
        }
#pragma unroll
        for (int j = 0; j < 8; ++j) {
            int d = sd0 + j;
            *(u16*)((char*)Vtlds + ((d * 128 + skey * 2) ^ ((d & 7) << 4))) = (u16)v0v[j];
        }
#pragma unroll
        for (int j = 0; j < 8; ++j) {
            int d = sd0 + 8 + j;
            *(u16*)((char*)Vtlds + ((d * 128 + skey * 2) ^ ((d & 7) << 4))) = (u16)v1v[j];
        }
        __syncthreads();

        // ---- QK^T: S[16 x 64] per wave ----
        f32x4 accS[4];
#pragma unroll
        for (int ni = 0; ni < 4; ++ni) accS[ni] = (f32x4){0.f, 0.f, 0.f, 0.f};
#pragma unroll
        for (int kk = 0; kk < 2; ++kk) {
#pragma unroll
            for (int ni = 0; ni < 4; ++ni) {
                int key = ni * 16 + l15;
                int kbyte = (key * 128 + kk * 64 + kh * 16) ^ ((key & 7) << 4);
                short8 kfrag = *(const short8*)((const char*)Klds + kbyte);
                accS[ni] = __builtin_amdgcn_mfma_f32_16x16x32_bf16(
                    qf[kk], kfrag, accS[ni], 0, 0, 0);
            }
        }

        // ---- mask + online softmax (per lane: 4 rows x 4 ni) ----
        const bool diag = (kb == qb);
        float pv_[4][4];
#pragma unroll
        for (int r = 0; r < 4; ++r) {
            const int grow = grow_base + r;
            float s0[4];
#pragma unroll
            for (int ni = 0; ni < 4; ++ni) {
                float sv = accS[ni][r] * 0.125f;
                if (diag && (kr0 + ni * 16 + l15) > grow) sv = -1e30f;
                s0[ni] = sv;
            }
            float mx = fmaxf(fmaxf(s0[0], s0[1]), fmaxf(s0[2], s0[3]));
            mx = fmaxf(mx, __shfl_xor(mx, 1));
            mx = fmaxf(mx, __shfl_xor(mx, 2));
            mx = fmaxf(mx, __shfl_xor(mx, 4));
            mx = fmaxf(mx, __shfl_xor(mx, 8));
            float newm = fmaxf(mrow[r], mx);
            float corr = __expf(mrow[r] - newm);
            float rs = 0.f;
#pragma unroll
            for (int ni = 0; ni < 4; ++ni) {
                float p = __expf(s0[ni] - newm);
                pv_[r][ni] = p;
                rs += p;
            }
            rs += __shfl_xor(rs, 1);
            rs += __shfl_xor(rs, 2);
            rs += __shfl_xor(rs, 4);
            rs += __shfl_xor(rs, 8);
            lrow[r] = lrow[r] * corr + rs;
            mrow[r] = newm;
#pragma unroll
            for (int ni = 0; ni < 4; ++ni) accO[ni][r] *= corr;
        }

        // ---- P (D-layout) -> LDS bf16 (A-layout readable) ----
#pragma unroll
        for (int r = 0; r < 4; ++r) {
            int prow = kh * 4 + r;
            int pswz = (prow & 7) << 4;
#pragma unroll
            for (int ni = 0; ni < 4; ++ni) {
                int pbyte = (prow * 128 + (ni * 16 + l15) * 2) ^ pswz;
                *(u16*)((char*)&Plds[w][0] + pbyte) = f2bf(pv_[r][ni]);
            }
        }

        // ---- PV: O += P[16 x 64] * V[64 keys x 64 d] ----
#pragma unroll
        for (int kk = 0; kk < 2; ++kk) {
            int pbyte = (l15 * 128 + kk * 64 + kh * 16) ^ ((l15 & 7) << 4);
            short8 pfrag = *(const short8*)((const char*)&Plds[w][0] + pbyte);
#pragma unroll
            for (int ni = 0; ni < 4; ++ni) {
                int d = ni * 16 + l15;
                int vbyte = (d * 128 + kk * 64 + kh * 16) ^ ((d & 7) << 4);
                short8 vfrag = *(const short8*)((const char*)Vtlds + vbyte);
                accO[ni] = __builtin_amdgcn_mfma_f32_16x16x32_bf16(
                    pfrag, vfrag, accO[ni], 0, 0, 0);
            }
        }
    }

    float inv[4];
#pragma unroll
    for (int r = 0; r < 4; ++r) inv[r] = 1.f / lrow[r];
#pragma unroll
    for (int ni = 0; ni < 4; ++ni)
#pragma unroll
        for (int r = 0; r < 4; ++r) {
            int srow = grow_base + r;
            int d = ni * 16 + l15;
            attn[((size_t)(b * SS + srow)) * HD + h * ATTND + d] =
                f2bf(accO[ni][r] * inv[r]);
        }
}

// ---------------------------------------------------------------------------
// Output projection MFMA: out[m,e] = sum_f A[m,f]*Wo[e,f] + bias[e].
// FIXED: A staging now 16 bf16/thread (R4 bug: was 8 -> half of As garbage).
// fp32 output.
// ---------------------------------------------------------------------------
__global__ __launch_bounds__(256) void outproj_mfma_kernel(const u16* __restrict__ A,
                                                           const float* __restrict__ Wo,
                                                           const float* __restrict__ bias,
                                                           float* __restrict__ out) {
    __shared__ u16 As[128][40];
    __shared__ u16 Bs[128][40];
    const int row0 = blockIdx.x * 128;
    const int col0 = blockIdx.y * 128;
    const int tid  = threadIdx.x;
    const int lane = tid & 63;
    const int wid  = tid >> 6;
    const int wm   = wid >> 1, wn = wid & 1;
    const int l15  = lane & 15, kh = lane >> 4;
    const int srow = tid >> 1, sh = tid & 1;

    f32x4 acc[4][4];
#pragma unroll
    for (int i = 0; i < 4; ++i)
#pragma unroll
        for (int j = 0; j < 4; ++j) acc[i][j] = (f32x4){0.f, 0.f, 0.f, 0.f};

    for (int k0 = 0; k0 < HD; k0 += 32) {
        short8 av0 = *(const short8*)&A[(size_t)(row0 + srow) * HD + k0 + sh * 16];
        short8 av1 = *(const short8*)&A[(size_t)(row0 + srow) * HD + k0 + sh * 16 + 8];
        float4 w4[4];
#pragma unroll
        for (int j = 0; j < 4; ++j)
            w4[j] = *(const float4*)&Wo[(size_t)(col0 + srow) * HD + k0 + sh * 16 + j * 4];

        __syncthreads();
        *(short8*)&As[srow][sh * 16]     = av0;
        *(short8*)&As[srow][sh * 16 + 8] = av1;
        short8 p0, p1;
        p0[0] = (short)f2bf(w4[0].x); p0[1] = (short)f2bf(w4[0].y);
        p0[2] = (short)f2bf(w4[0].z); p0[3] = (short)f2bf(w4[0].w);
        p0[4] = (short)f2bf(w4[1].x); p0[5] = (short)f2bf(w4[1].y);
        p0[6] = (short)f2bf(w4[1].z); p0[7] = (short)f2bf(w4[1].w);
        p1[0] = (short)f2bf(w4[2].x); p1[1] = (short)f2bf(w4[2].y);
        p1[2] = (short)f2bf(w4[2].z); p1[3] = (short)f2bf(w4[2].w);
        p1[4] = (short)f2bf(w4[3].x); p1[5] = (short)f2bf(w4[3].y);
        p1[6] = (short)f2bf(w4[3].z); p1[7] = (short)f2bf(w4[3].w);
        *(short8*)&Bs[srow][sh * 16]     = p0;
        *(short8*)&Bs[srow][sh * 16 + 8] = p1;
        __syncthreads();

        short8 af[4], bfr[4];
#pragma unroll
        for (int mi = 0; mi < 4; ++mi)
            af[mi] = *(const short8*)&As[wm * 64 + mi * 16 + l15][kh * 8];
#pragma unroll
        for (int ni = 0; ni < 4; ++ni)
            bfr[ni] = *(const short8*)&Bs[wn * 64 + ni * 16 + l15][kh * 8];
#pragma unroll
        for (int mi = 0; mi < 4; ++mi)
#pragma unroll
            for (int ni = 0; ni < 4; ++ni)
                acc[mi][ni] = __builtin_amdgcn_mfma_f32_16x16x32_bf16(
                    af[mi], bfr[ni], acc[mi][ni], 0, 0, 0);
    }

#pragma unroll
    for (int mi = 0; mi < 4; ++mi)
#pragma unroll
        for (int ni = 0; ni < 4; ++ni)
#pragma unroll
            for (int r = 0; r < 4; ++r) {
                int m   = row0 + wm * 64 + mi * 16 + kh * 4 + r;
                int col = col0 + wn * 64 + ni * 16 + l15;
                out[(size_t)m * EMB + col] = acc[mi][ni][r] + bias[col];
            }
}

// ---------------------------------------------------------------------------
extern "C" void kernel_launch(void* const* d_in, const int* in_sizes, int n_in,
                              void* d_out, int out_size, void* d_ws, size_t ws_size,
                              hipStream_t stream) {
    const float* q     = (const float*)d_in[0];
    const float* k     = (const float*)d_in[1];
    const float* v     = (const float*)d_in[2];
    // d_in[3] = mask (tril by construction; causal handled analytically)
    const float* w_q   = (const float*)d_in[4];
    const float* w_k   = (const float*)d_in[5];
    const float* w_v   = (const float*)d_in[6];
    const float* out_w = (const float*)d_in[7];
    const float* out_b = (const float*)d_in[8];

    u16* ws = (u16*)d_ws;
    const size_t MK = (size_t)MTOT * EMB;        // 4,194,304 elems
    u16* fq   = ws;                               // (B,H,S,D) bf16, 8 MiB
    u16* fk   = ws + MK;
    u16* fv   = ws + 2 * MK;
    u16* attn = ws + 3 * MK;                      // (B,S,HD) bf16, 8 MiB
    // total ws use: 32 MiB (proven OK in R9)

    dim3 gproj(MTOT / 128, HD / 128, 3);          // (32,8,3)
    proj_mfma_kernel<<<gproj, 256, 0, stream>>>(q, k, v, w_q, w_k, w_v, fq, fk, fv);

    dim3 gattn(BB * HEADS, SS / 64);              // (32,32)
    flash_mfma_kernel<<<gattn, 256, 0, stream>>>(fq, fk, fv, attn);

    dim3 gout(MTOT / 128, EMB / 128);             // (32,8)
    outproj_mfma_kernel<<<gout, 256, 0, stream>>>(attn, out_w, out_b, (float*)d_out);
}